// Round 10
// baseline (50248.532 us; speedup 1.0000x reference)
//
#include <hip/hip_runtime.h>

// HiPPO-LegS scan, chunked parallel formulation. L=1024,B=256,N=256 fp32.
//   x_t = A_t x_{t-1} + B_t*inp[t,b];  out[t,b,:] = x_t
// C=16 chunks of T=64:
//   Pass V (MODE 0): per-chunk zero-init scan -> v_end[c] (B,N)
//   Pass M (MODE 1): per-chunk cumulative matrix M^c, column-scan (x=e_j, u=0)
//   combine_all:     x_end[c] = M^c x_end[c-1] + v_end[c] (one launch, fp64 acc)
//   Pass F (MODE 2): re-scan chunk from x_start=x_end[c-1], write out
//
// ROUND 10: drop global_load_lds (R9: 47 GB/dispatch phantom HBM traffic on
// the scattered-DMA path; R6's identical API call was fine but under a
// different schedule — unmodellable, so removed). Staging is now reg-staged:
// plain global_load_dwordx4 -> (next phase) ds_write_b128. Normal loads are
// L2-cached; ds ops have exact lgkmcnt+barrier semantics; NO manual vmcnt.
// 3 consume phases (G0 | G1 | G2+G3), write-one-phase-after-load:
//   ph0: bar | ds_write CD(t) | out-store/scalars | consume G0(t) | load A(t+1)
//   ph1: bar | ds_write A(t+1) into G0 slots      | consume G1(t) | load B(t+1)
//   ph2: bar | ds_write B(t+1) into G1 slots      | consume G2+G3(t) |
//        load CD(t+1) | +input | bar | x-update
// Slot-group/consume-phase alignment and packed triangle layout = R9 (verified).

typedef float f32x4 __attribute__((ext_vector_type(4)));

#define LSTEPS  1024
#define BATCH   256
#define NDIM    256
#define NCH     16
#define TCH     64
#define NTHR    1024
#define NSLOT   132
#define XO      (NSLOT * 64 * 4)          // 33792 floats (A region)
#define XSTR    260
#define SMEMB   ((XO + 16 * XSTR) * 4)    // 151,808 B

__device__ __forceinline__ int tri4(int r) {   // prefix of per-row chunk counts
    const int a = r >> 2, bb = r & 3;
    return (a + 1) * (2 * a + bb);              // tri4(64)=544
}
__device__ __forceinline__ int offg(int r, int g) {  // row base within group g
    const int rho = r - 64 * g;
    return (rho < 64) ? tri4(rho) : 544 + 16 * (rho - 64);
}
__device__ __forceinline__ void lgkm0() {
    asm volatile("s_waitcnt lgkmcnt(0)" ::: "memory");
}
__device__ __forceinline__ void bar() {
    __builtin_amdgcn_s_barrier();
    asm volatile("" ::: "memory");
}

// consume k-group G: kc in [16G,16G+16). High rows always active for G<2
// (kHiHi>=33); low rows only possible for G<2 (kHiLo<=32).
#define CONSUME(G) \
    _Pragma("unroll") \
    for (int kk = 0; kk < 16; ++kk) { \
        const int kc = (G) * 16 + kk; \
        if ((G) < 2 || kc < kHiHi) { \
            const f32x4 xv = *(const f32x4*)&xl[v * XSTR + kc * 4]; \
            const f32x4 a2 = *(const f32x4*)&smem[(cbh2[(G)] + kc) * 4]; \
            const f32x4 a3 = *(const f32x4*)&smem[(cbh3[(G)] + kc) * 4]; \
            acc2 = fmaf(a2[0], xv[0], acc2); acc2 = fmaf(a2[1], xv[1], acc2); \
            acc2 = fmaf(a2[2], xv[2], acc2); acc2 = fmaf(a2[3], xv[3], acc2); \
            acc3 = fmaf(a3[0], xv[0], acc3); acc3 = fmaf(a3[1], xv[1], acc3); \
            acc3 = fmaf(a3[2], xv[2], acc3); acc3 = fmaf(a3[3], xv[3], acc3); \
            if ((G) < 2 && kc < kHiLo) { \
                const f32x4 a0 = *(const f32x4*)&smem[(cbl0[(G)] + kc) * 4]; \
                const f32x4 a1 = *(const f32x4*)&smem[(cbl1[(G)] + kc) * 4]; \
                acc0 = fmaf(a0[0], xv[0], acc0); acc0 = fmaf(a0[1], xv[1], acc0); \
                acc0 = fmaf(a0[2], xv[2], acc0); acc0 = fmaf(a0[3], xv[3], acc0); \
                acc1 = fmaf(a1[0], xv[0], acc1); acc1 = fmaf(a1[1], xv[1], acc1); \
                acc1 = fmaf(a1[2], xv[2], acc1); acc1 = fmaf(a1[3], xv[3], acc1); \
            } \
        } \
    }

template<int MODE>   // 0: v_end scan, 1: M-column scan, 2: final scan -> out
__global__ __launch_bounds__(NTHR)
void scan_pass(const float* __restrict__ inp, const float* __restrict__ A,
               const float* __restrict__ Bst, float* __restrict__ out,
               float* __restrict__ vendP, float* __restrict__ MP,
               const float* __restrict__ xendP)
{
    extern __shared__ float smem[];
    float* xl = smem + XO;
    const int T    = threadIdx.x;
    const int lane = T & 63, wave = T >> 6;
    const int v    = T & 15,  q    = (T >> 4) & 3;
    const int u    = wave * 4 + q;
    const int blk  = blockIdx.x;
    const int c     = 2 * (blk & 7) + ((blk >> 3) & 1);  // 2 chunks per XCD
    const int slice = blk >> 4;
    const int b0    = slice * 16;      // batch base (M0/2) or column base (M1)
    const int vv = wave, n4 = lane * 4;       // copy mapping: wave <-> vector

    const int r0 = 2 * u, r1 = 2 * u + 1, r2 = 254 - 2 * u, r3 = 255 - 2 * u;
    const int kHiLo = (u >> 1) + 1;               // chunks in rows r0/r1 (<=32)
    const int kHiHi = (r2 >> 2) + 1;              // chunks in rows r2/r3 (>=33)

    // per-(row,group) consume bases, padded group bases GB={0,3648,6272,7872}
    const int GB[4] = {0, 3648, 6272, 7872};
    int cbl0[2], cbl1[2], cbh2[4], cbh3[4];
#pragma unroll
    for (int g = 0; g < 2; ++g) {
        cbl0[g] = GB[g] + offg(r0, g) - 16 * g;
        cbl1[g] = GB[g] + offg(r1, g) - 16 * g;
    }
#pragma unroll
    for (int g = 0; g < 4; ++g) {
        cbh2[g] = GB[g] + offg(r2, g) - 16 * g;
        cbh3[g] = GB[g] + offg(r3, g) - 16 * g;
    }

    // staging map: 10 issues/wave; slot phases A[0,57) B[57,98) C[98,123) D[123,132)
    // p 0..3 = group A (consumed ph0), 4..6 = B (ph1), 7..8 = C, 9 = D (ph2)
    int gsrc[10], lbase[10];
#pragma unroll
    for (int p = 0; p < 10; ++p) {
        int slot;
        if (p < 4)      slot = (16 * p + wave) % 57;
        else if (p < 7) slot = 57 + (16 * (p - 4) + wave) % 41;
        else if (p < 9) slot = 98 + (16 * (p - 7) + wave) % 25;
        else            slot = 123 + (wave % 9);
        const int C = slot * 64 + lane;           // padded chunk index
        int g, gb, rs;
        if      (C >= 7872) { g = 3; gb = 7872; rs = 544;  }
        else if (C >= 6272) { g = 2; gb = 6272; rs = 1568; }
        else if (C >= 3648) { g = 1; gb = 3648; rs = 2592; }
        else                { g = 0; gb = 0;    rs = 3616; }
        const int cc = C - gb;
        int src = 0;                              // pad chunk: dummy A[0:4]
        if (cc < rs) {
            int r, kc;
            if (cc < 544) {
                int rl = 0, rh = 63;
                while (rl < rh) { const int mid = (rl + rh + 1) >> 1;
                                  if (tri4(mid) <= cc) rl = mid; else rh = mid - 1; }
                r = 64 * g + rl; kc = 16 * g + (cc - tri4(rl));
            } else {
                r = 64 * g + 64 + ((cc - 544) >> 4); kc = 16 * g + ((cc - 544) & 15);
            }
            src = r * NDIM + kc * 4;
        }
        gsrc[p]  = src;
        lbase[p] = slot * 256 + lane * 4;         // this lane's ds_write target
    }

    // x init
    {
        f32x4 xi = f32x4{0.f, 0.f, 0.f, 0.f};
        if (MODE == 2 && c > 0)
            xi = *(const f32x4*)&xendP[((size_t)(c - 1) * BATCH + b0 + vv) * NDIM + n4];
        *(f32x4*)&xl[vv * XSTR + n4] = xi;
        if (MODE == 1) {
            __syncthreads();
            if (T < 16) xl[T * XSTR + b0 + T] = 1.f;   // x^v = e_{b0+v}
        }
    }

    // prologue: stage all 10 quads of A(first step) via regs, drain, barrier
    {
        const float* At0 = A + (size_t)(c * TCH) * (NDIM * NDIM);
        f32x4 st[10];
#pragma unroll
        for (int p = 0; p < 10; ++p) st[p] = *(const f32x4*)(At0 + gsrc[p]);
#pragma unroll
        for (int p = 0; p < 10; ++p) *(f32x4*)&smem[lbase[p]] = st[p];
    }
    lgkm0(); bar();

    f32x4 stA[4], stB[3], stCD[3];

    for (int t = 0; t < TCH; ++t) {
        const int gt = c * TCH + t;
        const float* An = A + (size_t)((gt + 1 < LSTEPS) ? gt + 1 : gt) * (NDIM * NDIM);

        float acc0 = 0.f, acc1 = 0.f, acc2 = 0.f, acc3 = 0.f;
        float sIn = 0.f, sB0 = 0.f, sB1 = 0.f, sB2 = 0.f, sB3 = 0.f;

        // ---- ph0: consume G0(t) ----  (top barrier also publishes x(t-1))
        if (t > 0) {
#pragma unroll
            for (int p = 0; p < 3; ++p) *(f32x4*)&smem[lbase[7 + p]] = stCD[p];
        }
        if (MODE == 2 && t > 0) {
            const f32x4 xo = *(const f32x4*)&xl[vv * XSTR + n4];
            *(f32x4*)&out[((size_t)(gt - 1) * BATCH + b0 + vv) * NDIM + n4] = xo;
        }
        if (MODE != 1) {
            sIn = inp[gt * BATCH + b0 + v];
            sB0 = Bst[gt * NDIM + r0]; sB1 = Bst[gt * NDIM + r1];
            sB2 = Bst[gt * NDIM + r2]; sB3 = Bst[gt * NDIM + r3];
        }
#pragma unroll
        for (int p = 0; p < 4; ++p) stA[p] = *(const f32x4*)(An + gsrc[p]);  // A(t+1)
        CONSUME(0);

        // ---- ph1: consume G1(t); publish A(t+1) into G0 slots ----
        lgkm0(); bar();
#pragma unroll
        for (int p = 0; p < 4; ++p) *(f32x4*)&smem[lbase[p]] = stA[p];
#pragma unroll
        for (int p = 0; p < 3; ++p) stB[p] = *(const f32x4*)(An + gsrc[4 + p]); // B(t+1)
        CONSUME(1);

        // ---- ph2: consume G2+G3(t); publish B(t+1) into G1 slots ----
        lgkm0(); bar();
#pragma unroll
        for (int p = 0; p < 3; ++p) *(f32x4*)&smem[lbase[4 + p]] = stB[p];
#pragma unroll
        for (int p = 0; p < 3; ++p) stCD[p] = *(const f32x4*)(An + gsrc[7 + p]); // CD(t+1)
        CONSUME(2);
        CONSUME(3);

        float y0 = acc0, y1 = acc1, y2 = acc2, y3 = acc3;
        if (MODE != 1) {
            y0 = fmaf(sIn, sB0, y0); y1 = fmaf(sIn, sB1, y1);
            y2 = fmaf(sIn, sB2, y2); y3 = fmaf(sIn, sB3, y3);
        }
        lgkm0(); bar();   // all x/A reads of step t complete before x update
        xl[v * XSTR + r0] = y0; xl[v * XSTR + r1] = y1;
        xl[v * XSTR + r2] = y2; xl[v * XSTR + r3] = y3;
        lgkm0(); bar();   // publish x(t) (and guard CD-write of next ph0)
    }

    const f32x4 xf = *(const f32x4*)&xl[vv * XSTR + n4];
    if (MODE == 0) *(f32x4*)&vendP[((size_t)c * BATCH + b0 + vv) * NDIM + n4] = xf;
    if (MODE == 1) *(f32x4*)&MP[((size_t)c * NDIM + b0 + vv) * NDIM + n4] = xf;
    if (MODE == 2) *(f32x4*)&out[((size_t)(c * TCH + TCH - 1) * BATCH + b0 + vv) * NDIM + n4] = xf;
}

// x_end[c] = M^c x_end[c-1] + v_end[c]; 64 blocks x 4 batches, c sequential,
// fp64 accumulation. M col-major: M[c][j][i] = (M^c)_{i,j}
__global__ __launch_bounds__(1024)
void combine_all(const float* __restrict__ vend, const float* __restrict__ M,
                 float* __restrict__ xend)
{
    __shared__ float p[4][NDIM];
    const int i  = threadIdx.x & 255;
    const int bb = threadIdx.x >> 8;
    const int b  = blockIdx.x * 4 + bb;
    float x = vend[(size_t)b * NDIM + i];          // x_end[0] = v_end[0]
    xend[(size_t)b * NDIM + i] = x;
    for (int c = 1; c < NCH; ++c) {
        __syncthreads();
        p[bb][i] = x;
        __syncthreads();
        double acc = (double)vend[((size_t)c * BATCH + b) * NDIM + i];
        const float* Mc = M + (size_t)c * NDIM * NDIM;
#pragma unroll 8
        for (int j = 0; j < NDIM; ++j)
            acc += (double)Mc[j * NDIM + i] * (double)p[bb][j];
        x = (float)acc;
        xend[((size_t)c * BATCH + b) * NDIM + i] = x;
    }
}

// fallback (only if ws_size < 4MB): simple correct scan
__global__ __launch_bounds__(256)
void hippo_naive(const float* __restrict__ inp, const float* __restrict__ A,
                 const float* __restrict__ Bst, float* __restrict__ out)
{
    __shared__ float xs[2][NDIM];
    const int b = blockIdx.x, i = threadIdx.x;
    xs[0][i] = 0.f; __syncthreads();
    for (int t = 0; t < LSTEPS; ++t) {
        const float* At = A + (size_t)t * NDIM * NDIM + (size_t)i * NDIM;
        const float* xc = xs[t & 1];
        float acc = 0.f;
        for (int k = 0; k <= i; ++k) acc = fmaf(At[k], xc[k], acc);
        acc = fmaf(inp[t * BATCH + b], Bst[t * NDIM + i], acc);
        xs[(t & 1) ^ 1][i] = acc;
        out[((size_t)t * BATCH + b) * NDIM + i] = acc;
        __syncthreads();
    }
}

extern "C" void kernel_launch(void* const* d_in, const int* in_sizes, int n_in,
                              void* d_out, int out_size, void* d_ws, size_t ws_size,
                              hipStream_t stream) {
    const float* inp = (const float*)d_in[0];  // (L, BATCH)
    const float* A   = (const float*)d_in[1];  // (L, N, N)
    const float* Bst = (const float*)d_in[2];  // (L, N)
    float* out = (float*)d_out;                // (L, BATCH, N)

    const size_t needWs = (size_t)NCH * BATCH * NDIM * sizeof(float);  // 4 MB
    if (ws_size < needWs) {
        hipLaunchKernelGGL(hippo_naive, dim3(BATCH), dim3(NDIM), 0, stream,
                           inp, A, Bst, out);
        return;
    }
    // scratch inside out (stream-serialized; pass F overwrites all of out):
    float* vendP = out;                                 // [16][256][256]
    float* MP    = out + (size_t)NCH * BATCH * NDIM;    // [16][256][256] col-major
    float* xendP = (float*)d_ws;                        // [16][256][256]

    (void)hipFuncSetAttribute((const void*)scan_pass<0>,
                              hipFuncAttributeMaxDynamicSharedMemorySize, SMEMB);
    (void)hipFuncSetAttribute((const void*)scan_pass<1>,
                              hipFuncAttributeMaxDynamicSharedMemorySize, SMEMB);
    (void)hipFuncSetAttribute((const void*)scan_pass<2>,
                              hipFuncAttributeMaxDynamicSharedMemorySize, SMEMB);

    hipLaunchKernelGGL(scan_pass<0>, dim3(256), dim3(NTHR), SMEMB, stream,
                       inp, A, Bst, out, vendP, MP, (const float*)xendP);
    hipLaunchKernelGGL(scan_pass<1>, dim3(256), dim3(NTHR), SMEMB, stream,
                       inp, A, Bst, out, vendP, MP, (const float*)xendP);
    hipLaunchKernelGGL(combine_all, dim3(64), dim3(1024), 0, stream,
                       vendP, MP, xendP);
    hipLaunchKernelGGL(scan_pass<2>, dim3(256), dim3(NTHR), SMEMB, stream,
                       inp, A, Bst, out, vendP, MP, (const float*)xendP);
}

// Round 11
// 50243.326 us; speedup vs baseline: 1.0001x; 1.0001x over previous
//
#include <hip/hip_runtime.h>

// HiPPO-LegS scan, chunked parallel formulation. L=1024,B=256,N=256 fp32.
//   x_t = A_t x_{t-1} + B_t*inp[t,b];  out[t,b,:] = x_t
// C=16 chunks of T=64:
//   Pass V (MODE 0): per-chunk zero-init scan -> v_end[c] (B,N)
//   Pass M (MODE 1): per-chunk cumulative matrix M^c, column-scan (x=e_j, u=0)
//   combine_all:     x_end[c] = M^c x_end[c-1] + v_end[c] (one launch, fp64 acc)
//   Pass F (MODE 2): re-scan chunk from x_start=x_end[c-1], write out
//
// ROUND 11: __launch_bounds__(1024, 4). R9/R10's 48GB/dispatch phantom HBM
// traffic was per-step scratch spill/fill: default launch_bounds made hipcc
// target 64 VGPRs (chasing 2 blocks/CU that 151KB LDS forbids), and the loop
// body (10 staging quads + ~32 address ints live across consume phases)
// spilled to HBM-backed scratch every step. Evidence: traffic identical
// between DMA (R9) and reg-staged (R10) variants, WRITE~FETCH~8x requests,
// VGPR_Count=64. Declaring 4 waves/EU (= the inevitable 1 block/CU) raises
// the cap to 128.
//
// Staging (R10, verified): plain global_load_dwordx4 -> next-phase ds_write.
// 3 consume phases (G0 | G1 | G2+G3), write-one-phase-after-load:
//   ph0: bar | ds_write CD(t) | out-store/scalars | consume G0(t) | load A(t+1)
//   ph1: bar | ds_write A(t+1) into G0 slots      | consume G1(t) | load B(t+1)
//   ph2: bar | ds_write B(t+1) into G1 slots      | consume G2+G3(t) |
//        load CD(t+1) | +input | bar | x-update | bar
// Slot-group/consume-phase alignment and packed triangle layout = R9 (verified).

typedef float f32x4 __attribute__((ext_vector_type(4)));

#define LSTEPS  1024
#define BATCH   256
#define NDIM    256
#define NCH     16
#define TCH     64
#define NTHR    1024
#define NSLOT   132
#define XO      (NSLOT * 64 * 4)          // 33792 floats (A region)
#define XSTR    260
#define SMEMB   ((XO + 16 * XSTR) * 4)    // 151,808 B

__device__ __forceinline__ int tri4(int r) {   // prefix of per-row chunk counts
    const int a = r >> 2, bb = r & 3;
    return (a + 1) * (2 * a + bb);              // tri4(64)=544
}
__device__ __forceinline__ int offg(int r, int g) {  // row base within group g
    const int rho = r - 64 * g;
    return (rho < 64) ? tri4(rho) : 544 + 16 * (rho - 64);
}
__device__ __forceinline__ void lgkm0() {
    asm volatile("s_waitcnt lgkmcnt(0)" ::: "memory");
}
__device__ __forceinline__ void bar() {
    __builtin_amdgcn_s_barrier();
    asm volatile("" ::: "memory");
}

// consume k-group G: kc in [16G,16G+16). High rows always active for G<2
// (kHiHi>=33); low rows only possible for G<2 (kHiLo<=32).
#define CONSUME(G) \
    _Pragma("unroll") \
    for (int kk = 0; kk < 16; ++kk) { \
        const int kc = (G) * 16 + kk; \
        if ((G) < 2 || kc < kHiHi) { \
            const f32x4 xv = *(const f32x4*)&xl[v * XSTR + kc * 4]; \
            const f32x4 a2 = *(const f32x4*)&smem[(cbh2[(G)] + kc) * 4]; \
            const f32x4 a3 = *(const f32x4*)&smem[(cbh3[(G)] + kc) * 4]; \
            acc2 = fmaf(a2[0], xv[0], acc2); acc2 = fmaf(a2[1], xv[1], acc2); \
            acc2 = fmaf(a2[2], xv[2], acc2); acc2 = fmaf(a2[3], xv[3], acc2); \
            acc3 = fmaf(a3[0], xv[0], acc3); acc3 = fmaf(a3[1], xv[1], acc3); \
            acc3 = fmaf(a3[2], xv[2], acc3); acc3 = fmaf(a3[3], xv[3], acc3); \
            if ((G) < 2 && kc < kHiLo) { \
                const f32x4 a0 = *(const f32x4*)&smem[(cbl0[(G)] + kc) * 4]; \
                const f32x4 a1 = *(const f32x4*)&smem[(cbl1[(G)] + kc) * 4]; \
                acc0 = fmaf(a0[0], xv[0], acc0); acc0 = fmaf(a0[1], xv[1], acc0); \
                acc0 = fmaf(a0[2], xv[2], acc0); acc0 = fmaf(a0[3], xv[3], acc0); \
                acc1 = fmaf(a1[0], xv[0], acc1); acc1 = fmaf(a1[1], xv[1], acc1); \
                acc1 = fmaf(a1[2], xv[2], acc1); acc1 = fmaf(a1[3], xv[3], acc1); \
            } \
        } \
    }

template<int MODE>   // 0: v_end scan, 1: M-column scan, 2: final scan -> out
__global__ __launch_bounds__(NTHR, 4)
void scan_pass(const float* __restrict__ inp, const float* __restrict__ A,
               const float* __restrict__ Bst, float* __restrict__ out,
               float* __restrict__ vendP, float* __restrict__ MP,
               const float* __restrict__ xendP)
{
    extern __shared__ float smem[];
    float* xl = smem + XO;
    const int T    = threadIdx.x;
    const int lane = T & 63, wave = T >> 6;
    const int v    = T & 15,  q    = (T >> 4) & 3;
    const int u    = wave * 4 + q;
    const int blk  = blockIdx.x;
    const int c     = 2 * (blk & 7) + ((blk >> 3) & 1);  // 2 chunks per XCD
    const int slice = blk >> 4;
    const int b0    = slice * 16;      // batch base (M0/2) or column base (M1)
    const int vv = wave, n4 = lane * 4;       // copy mapping: wave <-> vector

    const int r0 = 2 * u, r1 = 2 * u + 1, r2 = 254 - 2 * u, r3 = 255 - 2 * u;
    const int kHiLo = (u >> 1) + 1;               // chunks in rows r0/r1 (<=32)
    const int kHiHi = (r2 >> 2) + 1;              // chunks in rows r2/r3 (>=33)

    // per-(row,group) consume bases, padded group bases GB={0,3648,6272,7872}
    const int GB[4] = {0, 3648, 6272, 7872};
    int cbl0[2], cbl1[2], cbh2[4], cbh3[4];
#pragma unroll
    for (int g = 0; g < 2; ++g) {
        cbl0[g] = GB[g] + offg(r0, g) - 16 * g;
        cbl1[g] = GB[g] + offg(r1, g) - 16 * g;
    }
#pragma unroll
    for (int g = 0; g < 4; ++g) {
        cbh2[g] = GB[g] + offg(r2, g) - 16 * g;
        cbh3[g] = GB[g] + offg(r3, g) - 16 * g;
    }

    // staging map: 10 issues/wave; slot phases A[0,57) B[57,98) C[98,123) D[123,132)
    // p 0..3 = group A (consumed ph0), 4..6 = B (ph1), 7..8 = C, 9 = D (ph2)
    int gsrc[10], lbase[10];
#pragma unroll
    for (int p = 0; p < 10; ++p) {
        int slot;
        if (p < 4)      slot = (16 * p + wave) % 57;
        else if (p < 7) slot = 57 + (16 * (p - 4) + wave) % 41;
        else if (p < 9) slot = 98 + (16 * (p - 7) + wave) % 25;
        else            slot = 123 + (wave % 9);
        const int C = slot * 64 + lane;           // padded chunk index
        int g, gb, rs;
        if      (C >= 7872) { g = 3; gb = 7872; rs = 544;  }
        else if (C >= 6272) { g = 2; gb = 6272; rs = 1568; }
        else if (C >= 3648) { g = 1; gb = 3648; rs = 2592; }
        else                { g = 0; gb = 0;    rs = 3616; }
        const int cc = C - gb;
        int src = 0;                              // pad chunk: dummy A[0:4]
        if (cc < rs) {
            int r, kc;
            if (cc < 544) {
                int rl = 0, rh = 63;
                while (rl < rh) { const int mid = (rl + rh + 1) >> 1;
                                  if (tri4(mid) <= cc) rl = mid; else rh = mid - 1; }
                r = 64 * g + rl; kc = 16 * g + (cc - tri4(rl));
            } else {
                r = 64 * g + 64 + ((cc - 544) >> 4); kc = 16 * g + ((cc - 544) & 15);
            }
            src = r * NDIM + kc * 4;
        }
        gsrc[p]  = src;
        lbase[p] = slot * 256 + lane * 4;         // this lane's ds_write target
    }

    // x init
    {
        f32x4 xi = f32x4{0.f, 0.f, 0.f, 0.f};
        if (MODE == 2 && c > 0)
            xi = *(const f32x4*)&xendP[((size_t)(c - 1) * BATCH + b0 + vv) * NDIM + n4];
        *(f32x4*)&xl[vv * XSTR + n4] = xi;
        if (MODE == 1) {
            __syncthreads();
            if (T < 16) xl[T * XSTR + b0 + T] = 1.f;   // x^v = e_{b0+v}
        }
    }

    // prologue: stage all 10 quads of A(first step) via regs, drain, barrier
    {
        const float* At0 = A + (size_t)(c * TCH) * (NDIM * NDIM);
        f32x4 st[10];
#pragma unroll
        for (int p = 0; p < 10; ++p) st[p] = *(const f32x4*)(At0 + gsrc[p]);
#pragma unroll
        for (int p = 0; p < 10; ++p) *(f32x4*)&smem[lbase[p]] = st[p];
    }
    lgkm0(); bar();

    f32x4 stA[4], stB[3], stCD[3];

    for (int t = 0; t < TCH; ++t) {
        const int gt = c * TCH + t;
        const float* An = A + (size_t)((gt + 1 < LSTEPS) ? gt + 1 : gt) * (NDIM * NDIM);

        float acc0 = 0.f, acc1 = 0.f, acc2 = 0.f, acc3 = 0.f;
        float sIn = 0.f, sB0 = 0.f, sB1 = 0.f, sB2 = 0.f, sB3 = 0.f;

        // ---- ph0: consume G0(t) ----  (top barrier also publishes x(t-1))
        if (t > 0) {
#pragma unroll
            for (int p = 0; p < 3; ++p) *(f32x4*)&smem[lbase[7 + p]] = stCD[p];
        }
        if (MODE == 2 && t > 0) {
            const f32x4 xo = *(const f32x4*)&xl[vv * XSTR + n4];
            *(f32x4*)&out[((size_t)(gt - 1) * BATCH + b0 + vv) * NDIM + n4] = xo;
        }
        if (MODE != 1) {
            sIn = inp[gt * BATCH + b0 + v];
            sB0 = Bst[gt * NDIM + r0]; sB1 = Bst[gt * NDIM + r1];
            sB2 = Bst[gt * NDIM + r2]; sB3 = Bst[gt * NDIM + r3];
        }
#pragma unroll
        for (int p = 0; p < 4; ++p) stA[p] = *(const f32x4*)(An + gsrc[p]);  // A(t+1)
        CONSUME(0);

        // ---- ph1: consume G1(t); publish A(t+1) into G0 slots ----
        lgkm0(); bar();
#pragma unroll
        for (int p = 0; p < 4; ++p) *(f32x4*)&smem[lbase[p]] = stA[p];
#pragma unroll
        for (int p = 0; p < 3; ++p) stB[p] = *(const f32x4*)(An + gsrc[4 + p]); // B(t+1)
        CONSUME(1);

        // ---- ph2: consume G2+G3(t); publish B(t+1) into G1 slots ----
        lgkm0(); bar();
#pragma unroll
        for (int p = 0; p < 3; ++p) *(f32x4*)&smem[lbase[4 + p]] = stB[p];
#pragma unroll
        for (int p = 0; p < 3; ++p) stCD[p] = *(const f32x4*)(An + gsrc[7 + p]); // CD(t+1)
        CONSUME(2);
        CONSUME(3);

        float y0 = acc0, y1 = acc1, y2 = acc2, y3 = acc3;
        if (MODE != 1) {
            y0 = fmaf(sIn, sB0, y0); y1 = fmaf(sIn, sB1, y1);
            y2 = fmaf(sIn, sB2, y2); y3 = fmaf(sIn, sB3, y3);
        }
        lgkm0(); bar();   // all x/A reads of step t complete before x update
        xl[v * XSTR + r0] = y0; xl[v * XSTR + r1] = y1;
        xl[v * XSTR + r2] = y2; xl[v * XSTR + r3] = y3;
        lgkm0(); bar();   // publish x(t) (and guard CD-write of next ph0)
    }

    const f32x4 xf = *(const f32x4*)&xl[vv * XSTR + n4];
    if (MODE == 0) *(f32x4*)&vendP[((size_t)c * BATCH + b0 + vv) * NDIM + n4] = xf;
    if (MODE == 1) *(f32x4*)&MP[((size_t)c * NDIM + b0 + vv) * NDIM + n4] = xf;
    if (MODE == 2) *(f32x4*)&out[((size_t)(c * TCH + TCH - 1) * BATCH + b0 + vv) * NDIM + n4] = xf;
}

// x_end[c] = M^c x_end[c-1] + v_end[c]; 64 blocks x 4 batches, c sequential,
// fp64 accumulation. M col-major: M[c][j][i] = (M^c)_{i,j}
__global__ __launch_bounds__(1024, 4)
void combine_all(const float* __restrict__ vend, const float* __restrict__ M,
                 float* __restrict__ xend)
{
    __shared__ float p[4][NDIM];
    const int i  = threadIdx.x & 255;
    const int bb = threadIdx.x >> 8;
    const int b  = blockIdx.x * 4 + bb;
    float x = vend[(size_t)b * NDIM + i];          // x_end[0] = v_end[0]
    xend[(size_t)b * NDIM + i] = x;
    for (int c = 1; c < NCH; ++c) {
        __syncthreads();
        p[bb][i] = x;
        __syncthreads();
        double acc = (double)vend[((size_t)c * BATCH + b) * NDIM + i];
        const float* Mc = M + (size_t)c * NDIM * NDIM;
#pragma unroll 8
        for (int j = 0; j < NDIM; ++j)
            acc += (double)Mc[j * NDIM + i] * (double)p[bb][j];
        x = (float)acc;
        xend[((size_t)c * BATCH + b) * NDIM + i] = x;
    }
}

// fallback (only if ws_size < 4MB): simple correct scan
__global__ __launch_bounds__(256)
void hippo_naive(const float* __restrict__ inp, const float* __restrict__ A,
                 const float* __restrict__ Bst, float* __restrict__ out)
{
    __shared__ float xs[2][NDIM];
    const int b = blockIdx.x, i = threadIdx.x;
    xs[0][i] = 0.f; __syncthreads();
    for (int t = 0; t < LSTEPS; ++t) {
        const float* At = A + (size_t)t * NDIM * NDIM + (size_t)i * NDIM;
        const float* xc = xs[t & 1];
        float acc = 0.f;
        for (int k = 0; k <= i; ++k) acc = fmaf(At[k], xc[k], acc);
        acc = fmaf(inp[t * BATCH + b], Bst[t * NDIM + i], acc);
        xs[(t & 1) ^ 1][i] = acc;
        out[((size_t)t * BATCH + b) * NDIM + i] = acc;
        __syncthreads();
    }
}

extern "C" void kernel_launch(void* const* d_in, const int* in_sizes, int n_in,
                              void* d_out, int out_size, void* d_ws, size_t ws_size,
                              hipStream_t stream) {
    const float* inp = (const float*)d_in[0];  // (L, BATCH)
    const float* A   = (const float*)d_in[1];  // (L, N, N)
    const float* Bst = (const float*)d_in[2];  // (L, N)
    float* out = (float*)d_out;                // (L, BATCH, N)

    const size_t needWs = (size_t)NCH * BATCH * NDIM * sizeof(float);  // 4 MB
    if (ws_size < needWs) {
        hipLaunchKernelGGL(hippo_naive, dim3(BATCH), dim3(NDIM), 0, stream,
                           inp, A, Bst, out);
        return;
    }
    // scratch inside out (stream-serialized; pass F overwrites all of out):
    float* vendP = out;                                 // [16][256][256]
    float* MP    = out + (size_t)NCH * BATCH * NDIM;    // [16][256][256] col-major
    float* xendP = (float*)d_ws;                        // [16][256][256]

    (void)hipFuncSetAttribute((const void*)scan_pass<0>,
                              hipFuncAttributeMaxDynamicSharedMemorySize, SMEMB);
    (void)hipFuncSetAttribute((const void*)scan_pass<1>,
                              hipFuncAttributeMaxDynamicSharedMemorySize, SMEMB);
    (void)hipFuncSetAttribute((const void*)scan_pass<2>,
                              hipFuncAttributeMaxDynamicSharedMemorySize, SMEMB);

    hipLaunchKernelGGL(scan_pass<0>, dim3(256), dim3(NTHR), SMEMB, stream,
                       inp, A, Bst, out, vendP, MP, (const float*)xendP);
    hipLaunchKernelGGL(scan_pass<1>, dim3(256), dim3(NTHR), SMEMB, stream,
                       inp, A, Bst, out, vendP, MP, (const float*)xendP);
    hipLaunchKernelGGL(combine_all, dim3(64), dim3(1024), 0, stream,
                       vendP, MP, xendP);
    hipLaunchKernelGGL(scan_pass<2>, dim3(256), dim3(NTHR), SMEMB, stream,
                       inp, A, Bst, out, vendP, MP, (const float*)xendP);
}

// Round 12
// 49850.473 us; speedup vs baseline: 1.0080x; 1.0079x over previous
//
#include <hip/hip_runtime.h>

// HiPPO-LegS scan, chunked parallel formulation. L=1024,B=256,N=256 fp32.
//   x_t = A_t x_{t-1} + B_t*inp[t,b];  out[t,b,:] = x_t
// C=16 chunks of T=64:
//   Pass V (MODE 0): per-chunk zero-init scan -> v_end[c] (B,N)
//   Pass M (MODE 1): per-chunk cumulative matrix M^c, column-scan (x=e_j, u=0)
//   combine_all:     x_end[c] = M^c x_end[c-1] + v_end[c] (one launch, fp64 acc)
//   Pass F (MODE 2): re-scan chunk from x_start=x_end[c-1], write out
//
// ROUND 12: kill the per-step scratch spill/fill (R9-R11: ~47GB/dispatch of
// phantom HBM traffic ~ 1.2MB/WG-step = per-16B line-granule scratch
// round-trips; WRITE>FETCH; VGPR pinned at 64 by the backend's occupancy
// heuristic, which __launch_bounds__ can only lower-bound, not pin).
//  (1) __attribute__((amdgpu_waves_per_eu(4,4))): pin occupancy target to the
//      LDS-forced reality (151KB => 1 block/CU = 4 waves/EU) -> 128-reg budget.
//  (2) register diet: gsrc[10]+lbase[10] fused into 10 packed u32 (both fit
//      16 bits); consume bases + kHiLo/kHiHi recomputed per phase (~25
//      VALU/step) instead of 14 persistent regs.
// Staging schedule (R10, verified): plain global_load_dwordx4 -> next-phase
// ds_write. 3 consume phases (G0 | G1 | G2+G3), write-one-phase-after-load.
// Packed-triangle k-group LDS layout, slot-aligned groups (R9, verified).

typedef float f32x4 __attribute__((ext_vector_type(4)));

#define LSTEPS  1024
#define BATCH   256
#define NDIM    256
#define NCH     16
#define TCH     64
#define NTHR    1024
#define NSLOT   132
#define XO      (NSLOT * 64 * 4)          // 33792 floats (A region)
#define XSTR    260
#define SMEMB   ((XO + 16 * XSTR) * 4)    // 151,808 B

__device__ __forceinline__ int tri4(int r) {   // prefix of per-row chunk counts
    const int a = r >> 2, bb = r & 3;
    return (a + 1) * (2 * a + bb);              // tri4(64)=544
}
// consume base for row r, k-group g: LDS chunk addr = cbase + kc
__device__ __forceinline__ int cbase(int r, int g) {
    const int GB = (g == 0) ? 0 : (g == 1) ? 3648 : (g == 2) ? 6272 : 7872;
    const int rho = r - 64 * g;
    const int off = (rho < 64) ? tri4(rho) : 544 + 16 * (rho - 64);
    return GB + off - 16 * g;
}
__device__ __forceinline__ void lgkm0() {
    asm volatile("s_waitcnt lgkmcnt(0)" ::: "memory");
}
__device__ __forceinline__ void bar() {
    __builtin_amdgcn_s_barrier();
    asm volatile("" ::: "memory");
}

// consume k-group G: kc in [16G,16G+16). High rows always active for G<2
// (kHiHi>=33); low rows only possible for G<2 (kHiLo<=32).
// BH2/BH3/BL0/BL1 = per-phase consume bases; KHL/KHH row-extent guards.
#define CONSUME(G, BH2, BH3, BL0, BL1, KHL, KHH) \
    _Pragma("unroll") \
    for (int kk = 0; kk < 16; ++kk) { \
        const int kc = (G) * 16 + kk; \
        if ((G) < 2 || kc < (KHH)) { \
            const f32x4 xv = *(const f32x4*)&xl[v * XSTR + kc * 4]; \
            const f32x4 a2 = *(const f32x4*)&smem[((BH2) + kc) * 4]; \
            const f32x4 a3 = *(const f32x4*)&smem[((BH3) + kc) * 4]; \
            acc2 = fmaf(a2[0], xv[0], acc2); acc2 = fmaf(a2[1], xv[1], acc2); \
            acc2 = fmaf(a2[2], xv[2], acc2); acc2 = fmaf(a2[3], xv[3], acc2); \
            acc3 = fmaf(a3[0], xv[0], acc3); acc3 = fmaf(a3[1], xv[1], acc3); \
            acc3 = fmaf(a3[2], xv[2], acc3); acc3 = fmaf(a3[3], xv[3], acc3); \
            if ((G) < 2 && kc < (KHL)) { \
                const f32x4 a0 = *(const f32x4*)&smem[((BL0) + kc) * 4]; \
                const f32x4 a1 = *(const f32x4*)&smem[((BL1) + kc) * 4]; \
                acc0 = fmaf(a0[0], xv[0], acc0); acc0 = fmaf(a0[1], xv[1], acc0); \
                acc0 = fmaf(a0[2], xv[2], acc0); acc0 = fmaf(a0[3], xv[3], acc0); \
                acc1 = fmaf(a1[0], xv[0], acc1); acc1 = fmaf(a1[1], xv[1], acc1); \
                acc1 = fmaf(a1[2], xv[2], acc1); acc1 = fmaf(a1[3], xv[3], acc1); \
            } \
        } \
    }

template<int MODE>   // 0: v_end scan, 1: M-column scan, 2: final scan -> out
__global__ __launch_bounds__(NTHR)
__attribute__((amdgpu_waves_per_eu(4, 4)))
void scan_pass(const float* __restrict__ inp, const float* __restrict__ A,
               const float* __restrict__ Bst, float* __restrict__ out,
               float* __restrict__ vendP, float* __restrict__ MP,
               const float* __restrict__ xendP)
{
    extern __shared__ float smem[];
    float* xl = smem + XO;
    const int T    = threadIdx.x;
    const int lane = T & 63, wave = T >> 6;
    const int v    = T & 15;
    const int u    = wave * 4 + ((T >> 4) & 3);
    const int blk  = blockIdx.x;
    const int c     = 2 * (blk & 7) + ((blk >> 3) & 1);  // 2 chunks per XCD
    const int b0    = (blk >> 4) * 16;  // batch base (M0/2) or column base (M1)
    const int n4    = lane * 4;         // copy mapping: wave <-> vector

    const int r0 = 2 * u, r1 = 2 * u + 1, r2 = 254 - 2 * u, r3 = 255 - 2 * u;

    // staging map: 10 issues/wave; slot phases A[0,57) B[57,98) C[98,123) D[123,132)
    // p 0..3 = group A (consumed ph0), 4..6 = B (ph1), 7..8 = C, 9 = D (ph2)
    // pk[p] = (global float-offset of src chunk) | (LDS float-offset << 16)
    unsigned pk[10];
#pragma unroll
    for (int p = 0; p < 10; ++p) {
        int slot;
        if (p < 4)      slot = (16 * p + wave) % 57;
        else if (p < 7) slot = 57 + (16 * (p - 4) + wave) % 41;
        else if (p < 9) slot = 98 + (16 * (p - 7) + wave) % 25;
        else            slot = 123 + (wave % 9);
        const int C = slot * 64 + lane;           // padded chunk index
        int g, gb, rs;
        if      (C >= 7872) { g = 3; gb = 7872; rs = 544;  }
        else if (C >= 6272) { g = 2; gb = 6272; rs = 1568; }
        else if (C >= 3648) { g = 1; gb = 3648; rs = 2592; }
        else                { g = 0; gb = 0;    rs = 3616; }
        const int cc = C - gb;
        int src = 0;                              // pad chunk: dummy A[0:4]
        if (cc < rs) {
            int r, kc;
            if (cc < 544) {
                int rl = 0, rh = 63;
                while (rl < rh) { const int mid = (rl + rh + 1) >> 1;
                                  if (tri4(mid) <= cc) rl = mid; else rh = mid - 1; }
                r = 64 * g + rl; kc = 16 * g + (cc - tri4(rl));
            } else {
                r = 64 * g + 64 + ((cc - 544) >> 4); kc = 16 * g + ((cc - 544) & 15);
            }
            src = r * NDIM + kc * 4;              // < 65536: fits 16 bits
        }
        pk[p] = (unsigned)src | ((unsigned)(slot * 256 + n4) << 16);
    }
#define GSRC(p) ((int)(pk[p] & 0xffffu))
#define LDST(p) ((int)(pk[p] >> 16))

    // x init
    {
        f32x4 xi = f32x4{0.f, 0.f, 0.f, 0.f};
        if (MODE == 2 && c > 0)
            xi = *(const f32x4*)&xendP[((size_t)(c - 1) * BATCH + b0 + wave) * NDIM + n4];
        *(f32x4*)&xl[wave * XSTR + n4] = xi;
        if (MODE == 1) {
            __syncthreads();
            if (T < 16) xl[T * XSTR + b0 + T] = 1.f;   // x^v = e_{b0+v}
        }
    }

    // prologue: stage all 10 quads of A(first step) via regs, drain, barrier
    {
        const float* At0 = A + (size_t)(c * TCH) * (NDIM * NDIM);
        f32x4 st[10];
#pragma unroll
        for (int p = 0; p < 10; ++p) st[p] = *(const f32x4*)(At0 + GSRC(p));
#pragma unroll
        for (int p = 0; p < 10; ++p) *(f32x4*)&smem[LDST(p)] = st[p];
    }
    lgkm0(); bar();

    f32x4 stA[4], stB[3], stCD[3];

    for (int t = 0; t < TCH; ++t) {
        const int gt = c * TCH + t;
        const float* An = A + (size_t)((gt + 1 < LSTEPS) ? gt + 1 : gt) * (NDIM * NDIM);

        float acc0 = 0.f, acc1 = 0.f, acc2 = 0.f, acc3 = 0.f;
        float sIn = 0.f, sB0 = 0.f, sB1 = 0.f, sB2 = 0.f, sB3 = 0.f;

        // ---- ph0: consume G0(t) ----  (top barrier also publishes x(t-1))
        if (t > 0) {
#pragma unroll
            for (int p = 0; p < 3; ++p) *(f32x4*)&smem[LDST(7 + p)] = stCD[p];
        }
        if (MODE == 2 && t > 0) {
            const f32x4 xo = *(const f32x4*)&xl[wave * XSTR + n4];
            *(f32x4*)&out[((size_t)(gt - 1) * BATCH + b0 + wave) * NDIM + n4] = xo;
        }
        if (MODE != 1) {
            sIn = inp[gt * BATCH + b0 + v];
            sB0 = Bst[gt * NDIM + r0]; sB1 = Bst[gt * NDIM + r1];
            sB2 = Bst[gt * NDIM + r2]; sB3 = Bst[gt * NDIM + r3];
        }
#pragma unroll
        for (int p = 0; p < 4; ++p) stA[p] = *(const f32x4*)(An + GSRC(p));  // A(t+1)
        CONSUME(0, cbase(r2, 0), cbase(r3, 0), cbase(r0, 0), cbase(r1, 0),
                (u >> 1) + 1, (r2 >> 2) + 1);

        // ---- ph1: consume G1(t); publish A(t+1) into G0 slots ----
        lgkm0(); bar();
#pragma unroll
        for (int p = 0; p < 4; ++p) *(f32x4*)&smem[LDST(p)] = stA[p];
#pragma unroll
        for (int p = 0; p < 3; ++p) stB[p] = *(const f32x4*)(An + GSRC(4 + p)); // B(t+1)
        CONSUME(1, cbase(r2, 1), cbase(r3, 1), cbase(r0, 1), cbase(r1, 1),
                (u >> 1) + 1, (r2 >> 2) + 1);

        // ---- ph2: consume G2+G3(t); publish B(t+1) into G1 slots ----
        lgkm0(); bar();
#pragma unroll
        for (int p = 0; p < 3; ++p) *(f32x4*)&smem[LDST(4 + p)] = stB[p];
#pragma unroll
        for (int p = 0; p < 3; ++p) stCD[p] = *(const f32x4*)(An + GSRC(7 + p)); // CD(t+1)
        CONSUME(2, cbase(r2, 2), cbase(r3, 2), 0, 0, 0, (r2 >> 2) + 1);
        CONSUME(3, cbase(r2, 3), cbase(r3, 3), 0, 0, 0, (r2 >> 2) + 1);

        float y0 = acc0, y1 = acc1, y2 = acc2, y3 = acc3;
        if (MODE != 1) {
            y0 = fmaf(sIn, sB0, y0); y1 = fmaf(sIn, sB1, y1);
            y2 = fmaf(sIn, sB2, y2); y3 = fmaf(sIn, sB3, y3);
        }
        lgkm0(); bar();   // all x/A reads of step t complete before x update
        xl[v * XSTR + r0] = y0; xl[v * XSTR + r1] = y1;
        xl[v * XSTR + r2] = y2; xl[v * XSTR + r3] = y3;
        lgkm0(); bar();   // publish x(t) (and guard CD-write of next ph0)
    }

    const f32x4 xf = *(const f32x4*)&xl[wave * XSTR + n4];
    if (MODE == 0) *(f32x4*)&vendP[((size_t)c * BATCH + b0 + wave) * NDIM + n4] = xf;
    if (MODE == 1) *(f32x4*)&MP[((size_t)c * NDIM + b0 + wave) * NDIM + n4] = xf;
    if (MODE == 2) *(f32x4*)&out[((size_t)(c * TCH + TCH - 1) * BATCH + b0 + wave) * NDIM + n4] = xf;
}

// x_end[c] = M^c x_end[c-1] + v_end[c]; 64 blocks x 4 batches, c sequential,
// fp64 accumulation. M col-major: M[c][j][i] = (M^c)_{i,j}
__global__ __launch_bounds__(1024)
void combine_all(const float* __restrict__ vend, const float* __restrict__ M,
                 float* __restrict__ xend)
{
    __shared__ float p[4][NDIM];
    const int i  = threadIdx.x & 255;
    const int bb = threadIdx.x >> 8;
    const int b  = blockIdx.x * 4 + bb;
    float x = vend[(size_t)b * NDIM + i];          // x_end[0] = v_end[0]
    xend[(size_t)b * NDIM + i] = x;
    for (int c = 1; c < NCH; ++c) {
        __syncthreads();
        p[bb][i] = x;
        __syncthreads();
        double acc = (double)vend[((size_t)c * BATCH + b) * NDIM + i];
        const float* Mc = M + (size_t)c * NDIM * NDIM;
#pragma unroll 8
        for (int j = 0; j < NDIM; ++j)
            acc += (double)Mc[j * NDIM + i] * (double)p[bb][j];
        x = (float)acc;
        xend[((size_t)c * BATCH + b) * NDIM + i] = x;
    }
}

// fallback (only if ws_size < 4MB): simple correct scan
__global__ __launch_bounds__(256)
void hippo_naive(const float* __restrict__ inp, const float* __restrict__ A,
                 const float* __restrict__ Bst, float* __restrict__ out)
{
    __shared__ float xs[2][NDIM];
    const int b = blockIdx.x, i = threadIdx.x;
    xs[0][i] = 0.f; __syncthreads();
    for (int t = 0; t < LSTEPS; ++t) {
        const float* At = A + (size_t)t * NDIM * NDIM + (size_t)i * NDIM;
        const float* xc = xs[t & 1];
        float acc = 0.f;
        for (int k = 0; k <= i; ++k) acc = fmaf(At[k], xc[k], acc);
        acc = fmaf(inp[t * BATCH + b], Bst[t * NDIM + i], acc);
        xs[(t & 1) ^ 1][i] = acc;
        out[((size_t)t * BATCH + b) * NDIM + i] = acc;
        __syncthreads();
    }
}

extern "C" void kernel_launch(void* const* d_in, const int* in_sizes, int n_in,
                              void* d_out, int out_size, void* d_ws, size_t ws_size,
                              hipStream_t stream) {
    const float* inp = (const float*)d_in[0];  // (L, BATCH)
    const float* A   = (const float*)d_in[1];  // (L, N, N)
    const float* Bst = (const float*)d_in[2];  // (L, N)
    float* out = (float*)d_out;                // (L, BATCH, N)

    const size_t needWs = (size_t)NCH * BATCH * NDIM * sizeof(float);  // 4 MB
    if (ws_size < needWs) {
        hipLaunchKernelGGL(hippo_naive, dim3(BATCH), dim3(NDIM), 0, stream,
                           inp, A, Bst, out);
        return;
    }
    // scratch inside out (stream-serialized; pass F overwrites all of out):
    float* vendP = out;                                 // [16][256][256]
    float* MP    = out + (size_t)NCH * BATCH * NDIM;    // [16][256][256] col-major
    float* xendP = (float*)d_ws;                        // [16][256][256]

    (void)hipFuncSetAttribute((const void*)scan_pass<0>,
                              hipFuncAttributeMaxDynamicSharedMemorySize, SMEMB);
    (void)hipFuncSetAttribute((const void*)scan_pass<1>,
                              hipFuncAttributeMaxDynamicSharedMemorySize, SMEMB);
    (void)hipFuncSetAttribute((const void*)scan_pass<2>,
                              hipFuncAttributeMaxDynamicSharedMemorySize, SMEMB);

    hipLaunchKernelGGL(scan_pass<0>, dim3(256), dim3(NTHR), SMEMB, stream,
                       inp, A, Bst, out, vendP, MP, (const float*)xendP);
    hipLaunchKernelGGL(scan_pass<1>, dim3(256), dim3(NTHR), SMEMB, stream,
                       inp, A, Bst, out, vendP, MP, (const float*)xendP);
    hipLaunchKernelGGL(combine_all, dim3(64), dim3(1024), 0, stream,
                       vendP, MP, xendP);
    hipLaunchKernelGGL(scan_pass<2>, dim3(256), dim3(NTHR), SMEMB, stream,
                       inp, A, Bst, out, vendP, MP, (const float*)xendP);
}

// Round 13
// 48474.255 us; speedup vs baseline: 1.0366x; 1.0284x over previous
//
#include <hip/hip_runtime.h>

// HiPPO-LegS scan, chunked parallel formulation. L=1024,B=256,N=256 fp32.
//   x_t = A_t x_{t-1} + B_t*inp[t,b];  out[t,b,:] = x_t
// C=16 chunks of T=64:
//   Pass V (MODE 0): per-chunk zero-init scan -> v_end[c] (B,N)
//   Pass M (MODE 1): per-chunk cumulative matrix M^c, column-scan (x=e_j, u=0)
//   combine_all:     x_end[c] = M^c x_end[c-1] + v_end[c] (one launch, fp64 acc)
//   Pass F (MODE 2): re-scan chunk from x_start=x_end[c-1], write out
//
// ROUND 13: register-profile rebuild. R6 (same 1024-thr/151KB shape,
// global_load_lds, VGPR=52) was CLEAN (602MB/262MB); R9-12 (peak-live 75-110
// under the backend's stubborn 64-reg target) showed ~19GB/28GB phantom
// traffic. Fix = get peak-live back under 64 like R6:
//   (1) global_load_lds staging (in-flight A costs ZERO registers; deletes
//       the 40-reg stA/stB/stCD of R10-12),
//   (2) pk[10] packed u32 offsets (gsrc | lbase<<16) instead of 20 ints,
//   (3) consume bases recomputed per phase (cbase()) instead of 14 ints.
// Schedule = R9's 4-phase rolling-overwrite (numerically verified R9-12),
// with sink-robust MODE-independent vmcnt counts:
//   ph0: vmcnt(5)  forces A(t)  [newest allowed: B(t)3+C(t)2]
//   ph2: vmcnt(5)  forces C(t)  [newest allowed: A(t+1)4 +D(t)... >=2 slack]
//   ph3: vmcnt(7)  forces D(t)  [newest allowed: A(t+1)4+B(t+1)3]
// each followed by lgkmcnt(0) + s_barrier BEFORE consume (m201 rule).
// Packed-triangle k-group LDS layout, slot-aligned groups (R9, verified).

typedef float f32x4 __attribute__((ext_vector_type(4)));

#define LSTEPS  1024
#define BATCH   256
#define NDIM    256
#define NCH     16
#define TCH     64
#define NTHR    1024
#define NSLOT   132
#define XO      (NSLOT * 64 * 4)          // 33792 floats (A region)
#define XSTR    260
#define SMEMB   ((XO + 16 * XSTR) * 4)    // 151,808 B

__device__ __forceinline__ int tri4(int r) {   // prefix of per-row chunk counts
    const int a = r >> 2, bb = r & 3;
    return (a + 1) * (2 * a + bb);              // tri4(64)=544
}
// consume base for row r, k-group g: LDS chunk addr = cbase + kc
__device__ __forceinline__ int cbase(int r, int g) {
    const int GB = (g == 0) ? 0 : (g == 1) ? 3648 : (g == 2) ? 6272 : 7872;
    const int rho = r - 64 * g;
    const int off = (rho < 64) ? tri4(rho) : 544 + 16 * (rho - 64);
    return GB + off - 16 * g;
}
template<int N> __device__ __forceinline__ void vmw() {
    asm volatile("s_waitcnt vmcnt(%0)" :: "n"(N) : "memory");
}
__device__ __forceinline__ void lgkm0() {
    asm volatile("s_waitcnt lgkmcnt(0)" ::: "memory");
}
__device__ __forceinline__ void bar() {
    __builtin_amdgcn_s_barrier();
    asm volatile("" ::: "memory");
}
__device__ __forceinline__ void dma16(const float* g, float* l) {
    __builtin_amdgcn_global_load_lds((const __attribute__((address_space(1))) void*)g,
                                     (__attribute__((address_space(3))) void*)l, 16, 0, 0);
}

// consume k-group G: kc in [16G,16G+16). High rows always active for G<2
// (kHiHi>=33); low rows only possible for G<2 (kHiLo<=32).
#define CONSUME(G, BH2, BH3, BL0, BL1, KHL, KHH) \
    _Pragma("unroll") \
    for (int kk = 0; kk < 16; ++kk) { \
        const int kc = (G) * 16 + kk; \
        if ((G) < 2 || kc < (KHH)) { \
            const f32x4 xv = *(const f32x4*)&xl[v * XSTR + kc * 4]; \
            const f32x4 a2 = *(const f32x4*)&smem[((BH2) + kc) * 4]; \
            const f32x4 a3 = *(const f32x4*)&smem[((BH3) + kc) * 4]; \
            acc2 = fmaf(a2[0], xv[0], acc2); acc2 = fmaf(a2[1], xv[1], acc2); \
            acc2 = fmaf(a2[2], xv[2], acc2); acc2 = fmaf(a2[3], xv[3], acc2); \
            acc3 = fmaf(a3[0], xv[0], acc3); acc3 = fmaf(a3[1], xv[1], acc3); \
            acc3 = fmaf(a3[2], xv[2], acc3); acc3 = fmaf(a3[3], xv[3], acc3); \
            if ((G) < 2 && kc < (KHL)) { \
                const f32x4 a0 = *(const f32x4*)&smem[((BL0) + kc) * 4]; \
                const f32x4 a1 = *(const f32x4*)&smem[((BL1) + kc) * 4]; \
                acc0 = fmaf(a0[0], xv[0], acc0); acc0 = fmaf(a0[1], xv[1], acc0); \
                acc0 = fmaf(a0[2], xv[2], acc0); acc0 = fmaf(a0[3], xv[3], acc0); \
                acc1 = fmaf(a1[0], xv[0], acc1); acc1 = fmaf(a1[1], xv[1], acc1); \
                acc1 = fmaf(a1[2], xv[2], acc1); acc1 = fmaf(a1[3], xv[3], acc1); \
            } \
        } \
    }

template<int MODE>   // 0: v_end scan, 1: M-column scan, 2: final scan -> out
__global__ __launch_bounds__(NTHR)
void scan_pass(const float* __restrict__ inp, const float* __restrict__ A,
               const float* __restrict__ Bst, float* __restrict__ out,
               float* __restrict__ vendP, float* __restrict__ MP,
               const float* __restrict__ xendP)
{
    extern __shared__ float smem[];
    float* xl = smem + XO;
    const int T    = threadIdx.x;
    const int lane = T & 63, wave = T >> 6;
    const int v    = T & 15;
    const int u    = wave * 4 + ((T >> 4) & 3);
    const int blk  = blockIdx.x;
    const int c     = 2 * (blk & 7) + ((blk >> 3) & 1);  // 2 chunks per XCD
    const int b0    = (blk >> 4) * 16;  // batch base (M0/2) or column base (M1)
    const int n4    = lane * 4;

    const int r0 = 2 * u, r1 = 2 * u + 1, r2 = 254 - 2 * u, r3 = 255 - 2 * u;

    // staging map: 10 DMA issues/wave; slot phases A[0,57) B[57,98) C[98,123)
    // D[123,132). p 0..3 = A (consumed ph0), 4..6 = B (ph1), 7..8 = C (ph2),
    // 9 = D (ph3). pk = per-lane global float-offset | wave-uniform LDS
    // float-offset << 16 (DMA dest = base + lane*16B, HW-added).
    unsigned pk[10];
#pragma unroll
    for (int p = 0; p < 10; ++p) {
        int slot;
        if (p < 4)      slot = (16 * p + wave) % 57;
        else if (p < 7) slot = 57 + (16 * (p - 4) + wave) % 41;
        else if (p < 9) slot = 98 + (16 * (p - 7) + wave) % 25;
        else            slot = 123 + (wave % 9);
        const int C = slot * 64 + lane;           // padded chunk index
        int g, gb, rs;
        if      (C >= 7872) { g = 3; gb = 7872; rs = 544;  }
        else if (C >= 6272) { g = 2; gb = 6272; rs = 1568; }
        else if (C >= 3648) { g = 1; gb = 3648; rs = 2592; }
        else                { g = 0; gb = 0;    rs = 3616; }
        const int cc = C - gb;
        int src = 0;                              // pad chunk: dummy A[0:4]
        if (cc < rs) {
            int r, kc;
            if (cc < 544) {
                int rl = 0, rh = 63;
                while (rl < rh) { const int mid = (rl + rh + 1) >> 1;
                                  if (tri4(mid) <= cc) rl = mid; else rh = mid - 1; }
                r = 64 * g + rl; kc = 16 * g + (cc - tri4(rl));
            } else {
                r = 64 * g + 64 + ((cc - 544) >> 4); kc = 16 * g + ((cc - 544) & 15);
            }
            src = r * NDIM + kc * 4;              // < 65536: fits 16 bits
        }
        pk[p] = (unsigned)src | ((unsigned)(slot * 256) << 16);
    }
#define GSRC(p) ((int)(pk[p] & 0xffffu))
#define LDMA(p) ((int)(pk[p] >> 16))

    // x init
    {
        f32x4 xi = f32x4{0.f, 0.f, 0.f, 0.f};
        if (MODE == 2 && c > 0)
            xi = *(const f32x4*)&xendP[((size_t)(c - 1) * BATCH + b0 + wave) * NDIM + n4];
        *(f32x4*)&xl[wave * XSTR + n4] = xi;
        if (MODE == 1) {
            __syncthreads();
            if (T < 16) xl[T * XSTR + b0 + T] = 1.f;   // x^v = e_{b0+v}
        }
    }

    // prologue: stage all 4 groups of A(first step), full drain
    {
        const float* At0 = A + (size_t)(c * TCH) * (NDIM * NDIM);
#pragma unroll
        for (int p = 0; p < 10; ++p) dma16(At0 + GSRC(p), smem + LDMA(p));
    }
    asm volatile("s_waitcnt vmcnt(0) lgkmcnt(0)" ::: "memory");
    bar();

    for (int t = 0; t < TCH; ++t) {
        const int gt = c * TCH + t;
        const float* At = A + (size_t)gt * (NDIM * NDIM);
        const float* An = A + (size_t)((gt + 1 < LSTEPS) ? gt + 1 : gt) * (NDIM * NDIM);

        float acc0 = 0.f, acc1 = 0.f, acc2 = 0.f, acc3 = 0.f;
        float sIn = 0.f, sB0 = 0.f, sB1 = 0.f, sB2 = 0.f, sB3 = 0.f;

        // ---- ph0: consume G0(t). vmcnt(5): newest allowed = B(t)3+C(t)2,
        //      forces A(t)4 complete regardless of scalar-load placement ----
        vmw<5>(); lgkm0(); bar();
        dma16(At + GSRC(9), smem + LDMA(9));             // D(t), consumed ph3
        if (MODE == 2 && t > 0) {
            const f32x4 xo = *(const f32x4*)&xl[wave * XSTR + n4];
            *(f32x4*)&out[((size_t)(gt - 1) * BATCH + b0 + wave) * NDIM + n4] = xo;
        }
        if (MODE != 1) {
            sIn = inp[gt * BATCH + b0 + v];
            sB0 = Bst[gt * NDIM + r0]; sB1 = Bst[gt * NDIM + r1];
            sB2 = Bst[gt * NDIM + r2]; sB3 = Bst[gt * NDIM + r3];
        }
        CONSUME(0, cbase(r2, 0), cbase(r3, 0), cbase(r0, 0), cbase(r1, 0),
                (u >> 1) + 1, (r2 >> 2) + 1);

        // ---- ph1: consume G1(t) (B(t) forced by ph0's vmcnt(5)) ----
        lgkm0(); bar();
#pragma unroll
        for (int p = 0; p < 4; ++p) dma16(An + GSRC(p), smem + LDMA(p));   // A(t+1)
        CONSUME(1, cbase(r2, 1), cbase(r3, 1), cbase(r0, 1), cbase(r1, 1),
                (u >> 1) + 1, (r2 >> 2) + 1);

        // ---- ph2: consume G2(t). vmcnt(5): forces C(t) (A(t+1)4+D(t) newer) ----
        vmw<5>(); lgkm0(); bar();
#pragma unroll
        for (int p = 4; p < 7; ++p) dma16(An + GSRC(4 + (p - 4)), smem + LDMA(p)); // B(t+1)
        CONSUME(2, cbase(r2, 2), cbase(r3, 2), 0, 0, 0, (r2 >> 2) + 1);

        // ---- ph3: consume G3(t). vmcnt(7): forces D(t) (A'4+B'3 newer) ----
        vmw<7>(); lgkm0(); bar();
#pragma unroll
        for (int p = 7; p < 9; ++p) dma16(An + GSRC(p), smem + LDMA(p));   // C(t+1)
        CONSUME(3, cbase(r2, 3), cbase(r3, 3), 0, 0, 0, (r2 >> 2) + 1);

        float y0 = acc0, y1 = acc1, y2 = acc2, y3 = acc3;
        if (MODE != 1) {
            y0 = fmaf(sIn, sB0, y0); y1 = fmaf(sIn, sB1, y1);
            y2 = fmaf(sIn, sB2, y2); y3 = fmaf(sIn, sB3, y3);
        }
        lgkm0(); bar();   // all x/A reads of step t complete before x update
        xl[v * XSTR + r0] = y0; xl[v * XSTR + r1] = y1;
        xl[v * XSTR + r2] = y2; xl[v * XSTR + r3] = y3;
        // next ph0's lgkm0+bar publishes the new x
    }

    lgkm0(); bar();
    const f32x4 xf = *(const f32x4*)&xl[wave * XSTR + n4];
    if (MODE == 0) *(f32x4*)&vendP[((size_t)c * BATCH + b0 + wave) * NDIM + n4] = xf;
    if (MODE == 1) *(f32x4*)&MP[((size_t)c * NDIM + b0 + wave) * NDIM + n4] = xf;
    if (MODE == 2) *(f32x4*)&out[((size_t)(c * TCH + TCH - 1) * BATCH + b0 + wave) * NDIM + n4] = xf;
    asm volatile("s_waitcnt vmcnt(0)" ::: "memory");   // drain tail DMA
}

// x_end[c] = M^c x_end[c-1] + v_end[c]; 64 blocks x 4 batches, c sequential,
// fp64 accumulation. M col-major: M[c][j][i] = (M^c)_{i,j}
__global__ __launch_bounds__(1024)
void combine_all(const float* __restrict__ vend, const float* __restrict__ M,
                 float* __restrict__ xend)
{
    __shared__ float p[4][NDIM];
    const int i  = threadIdx.x & 255;
    const int bb = threadIdx.x >> 8;
    const int b  = blockIdx.x * 4 + bb;
    float x = vend[(size_t)b * NDIM + i];          // x_end[0] = v_end[0]
    xend[(size_t)b * NDIM + i] = x;
    for (int c = 1; c < NCH; ++c) {
        __syncthreads();
        p[bb][i] = x;
        __syncthreads();
        double acc = (double)vend[((size_t)c * BATCH + b) * NDIM + i];
        const float* Mc = M + (size_t)c * NDIM * NDIM;
#pragma unroll 8
        for (int j = 0; j < NDIM; ++j)
            acc += (double)Mc[j * NDIM + i] * (double)p[bb][j];
        x = (float)acc;
        xend[((size_t)c * BATCH + b) * NDIM + i] = x;
    }
}

// fallback (only if ws_size < 4MB): simple correct scan
__global__ __launch_bounds__(256)
void hippo_naive(const float* __restrict__ inp, const float* __restrict__ A,
                 const float* __restrict__ Bst, float* __restrict__ out)
{
    __shared__ float xs[2][NDIM];
    const int b = blockIdx.x, i = threadIdx.x;
    xs[0][i] = 0.f; __syncthreads();
    for (int t = 0; t < LSTEPS; ++t) {
        const float* At = A + (size_t)t * NDIM * NDIM + (size_t)i * NDIM;
        const float* xc = xs[t & 1];
        float acc = 0.f;
        for (int k = 0; k <= i; ++k) acc = fmaf(At[k], xc[k], acc);
        acc = fmaf(inp[t * BATCH + b], Bst[t * NDIM + i], acc);
        xs[(t & 1) ^ 1][i] = acc;
        out[((size_t)t * BATCH + b) * NDIM + i] = acc;
        __syncthreads();
    }
}

extern "C" void kernel_launch(void* const* d_in, const int* in_sizes, int n_in,
                              void* d_out, int out_size, void* d_ws, size_t ws_size,
                              hipStream_t stream) {
    const float* inp = (const float*)d_in[0];  // (L, BATCH)
    const float* A   = (const float*)d_in[1];  // (L, N, N)
    const float* Bst = (const float*)d_in[2];  // (L, N)
    float* out = (float*)d_out;                // (L, BATCH, N)

    const size_t needWs = (size_t)NCH * BATCH * NDIM * sizeof(float);  // 4 MB
    if (ws_size < needWs) {
        hipLaunchKernelGGL(hippo_naive, dim3(BATCH), dim3(NDIM), 0, stream,
                           inp, A, Bst, out);
        return;
    }
    // scratch inside out (stream-serialized; pass F overwrites all of out):
    float* vendP = out;                                 // [16][256][256]
    float* MP    = out + (size_t)NCH * BATCH * NDIM;    // [16][256][256] col-major
    float* xendP = (float*)d_ws;                        // [16][256][256]

    (void)hipFuncSetAttribute((const void*)scan_pass<0>,
                              hipFuncAttributeMaxDynamicSharedMemorySize, SMEMB);
    (void)hipFuncSetAttribute((const void*)scan_pass<1>,
                              hipFuncAttributeMaxDynamicSharedMemorySize, SMEMB);
    (void)hipFuncSetAttribute((const void*)scan_pass<2>,
                              hipFuncAttributeMaxDynamicSharedMemorySize, SMEMB);

    hipLaunchKernelGGL(scan_pass<0>, dim3(256), dim3(NTHR), SMEMB, stream,
                       inp, A, Bst, out, vendP, MP, (const float*)xendP);
    hipLaunchKernelGGL(scan_pass<1>, dim3(256), dim3(NTHR), SMEMB, stream,
                       inp, A, Bst, out, vendP, MP, (const float*)xendP);
    hipLaunchKernelGGL(combine_all, dim3(64), dim3(1024), 0, stream,
                       vendP, MP, xendP);
    hipLaunchKernelGGL(scan_pass<2>, dim3(256), dim3(NTHR), SMEMB, stream,
                       inp, A, Bst, out, vendP, MP, (const float*)xendP);
}

// Round 14
// 3461.412 us; speedup vs baseline: 14.5168x; 14.0042x over previous
//
#include <hip/hip_runtime.h>

// HiPPO-LegS forward scan: x_t = A_t x_{t-1} + B_t*inp[t,b]; out[t,b,:]=x_t.
// L=1024, BATCH=256, N=256, fp32. A_t lower-triangular.
//
// ROUND 14: abandon the chunked formulation (R9-R13: ~47GB/dispatch phantom
// HBM traffic invariant to staging mechanism & register budget — property of
// the 16-stream x 16-slice access shape, unmodellable from source). Return to
// the R6 structure (single chip-wide A-stream, PROVEN clean: 602MB/262MB,
// 3.38ms) with ONE change: BB=2 batches per WG, 128 WGs. R6's step time
// (7.9K cyc vs 1.5K VALU) fits per-XCD L2-broadcast saturation (32 CUs x
// 139KB/step); halving consumers halves that, VALU only doubles (~3K).
//
// Everything else R6-verbatim: packed-triangle LDS (H0: m<32 / H1: m>=32,
// 8320 x 16B chunks = 133KB), global_load_lds staging 7+3 slots/wave,
// 3 barriers + vmcnt(0)/vmcnt(3) per step, balanced rows
// {2g, 2g+1, 254-2g, 255-2g}. BB=2 butterfly = R3-verbatim (proven).

typedef float f32x4 __attribute__((ext_vector_type(4)));

#define LSTEPS   1024
#define BATCH    256
#define NDIM     256
#define NWG      128
#define BB       2
#define THREADS  1024
#define H0C      6208      // 16B chunks in H0 (= 97*64)
#define H1C      2112      // = 33*64
#define H0SLOTS  97
#define H1SLOTS  33
#define H0ISS    7
#define H1ISS    3
#define XPL      260       // floats per (plane,batch) x row (256+4 pad)
#define XSOFF    ((H0C + H1C) * 4)              // 33280 floats
#define SMEMB    ((XSOFF + 2 * BB * XPL) * 4)   // 137,280 B

__device__ __forceinline__ int rs0(int r) {  // chunks before row r in H0
    if (r >= 128) return 2112 + (r - 128) * 32;
    int q = r >> 2;
    return 2 * q * (q - 1) + (r - (q << 2)) * q + r;
}
__device__ __forceinline__ int rs1(int r) {  // chunks before row r in H1 (r>=128)
    int q = r >> 2;
    int S = 2 * q * (q - 1) + (r - (q << 2)) * q;
    return S - 1984 - 31 * (r - 128);
}
__device__ __forceinline__ int frow0(int c) {
    int lo = 0, hi = 255;
    while (lo < hi) { int mid = (lo + hi + 1) >> 1; if (rs0(mid) <= c) lo = mid; else hi = mid - 1; }
    return lo;
}
__device__ __forceinline__ int frow1(int c) {
    int lo = 128, hi = 255;
    while (lo < hi) { int mid = (lo + hi + 1) >> 1; if (rs1(mid) <= c) lo = mid; else hi = mid - 1; }
    return lo;
}
__device__ __forceinline__ void gload_lds16(const float* g, float* l) {
    __builtin_amdgcn_global_load_lds(
        (const __attribute__((address_space(1))) void*)g,
        (__attribute__((address_space(3))) void*)l, 16, 0, 0);
}

__global__ __launch_bounds__(THREADS)
void hippo_scan(const float* __restrict__ inp,   // (L, BATCH)
                const float* __restrict__ A,     // (L, N, N)
                const float* __restrict__ Bst,   // (L, N)
                float* __restrict__ out)         // (L, BATCH, N)
{
    extern __shared__ float smem[];
    float* Ab = smem;

    const int T    = threadIdx.x;
    const int lane = T & 63;
    const int wave = T >> 6;
    const int g    = T >> 4;       // 0..63 row-group
    const int s    = T & 15;       // 0..15 k-segment
    const int b0   = blockIdx.x * BB;

    int rows[4] = {2 * g, 2 * g + 1, 254 - 2 * g, 255 - 2 * g};
    const int bOwn = s & 1;
    const int sel1 = (s >> 1) & 1;
    const int sel2 = (s >> 2) & 1;
    const int rowOwn = rows[sel1 + 2 * sel2];
    const bool writer = (s < 8);   // 8 owners: 4 rows x 2 batches

    // FMA-read bases (float offsets) + per-row max active chunk index
    int a0base[4], mmax[4];
#pragma unroll
    for (int i = 0; i < 4; ++i) { a0base[i] = rs0(rows[i]) * 4; mmax[i] = rows[i] >> 2; }
    int a1base[2];
    a1base[0] = (H0C + rs1(rows[2]) - 32) * 4;
    a1base[1] = (H0C + rs1(rows[3]) - 32) * 4;

    // staging precompute (R6-verbatim): per-issue global float-offset
    // (per-lane) and LDS slot base (wave-uniform); dup slots re-DMA same data.
    int gsrc0[H0ISS], lbase0[H0ISS];
#pragma unroll
    for (int p = 0; p < H0ISS; ++p) {
        int slot = wave + 16 * p; if (slot >= H0SLOTS) slot -= 16;
        int c = slot * 64 + lane;
        int r = frow0(c);
        gsrc0[p]  = r * NDIM + (c - rs0(r)) * 4;
        lbase0[p] = slot * 256;
    }
    int gsrc1[H1ISS], lbase1[H1ISS];
#pragma unroll
    for (int p = 0; p < H1ISS; ++p) {
        int slot = wave + 16 * p; if (slot >= H1SLOTS) slot -= 16;
        int c = slot * 64 + lane;
        int r = frow1(c);
        gsrc1[p]  = r * NDIM + 128 + (c - rs1(r)) * 4;
        lbase1[p] = H0C * 4 + slot * 256;
    }

    // zero x state (2 planes x BB x XPL)
    for (int i = T; i < 2 * BB * XPL; i += THREADS) smem[XSOFF + i] = 0.f;

    // prologue: stage A_0, full drain
#pragma unroll
    for (int p = 0; p < H0ISS; ++p) gload_lds16(A + gsrc0[p], Ab + lbase0[p]);
#pragma unroll
    for (int p = 0; p < H1ISS; ++p) gload_lds16(A + gsrc1[p], Ab + lbase1[p]);
    asm volatile("s_waitcnt vmcnt(0) lgkmcnt(0)" ::: "memory");
    __builtin_amdgcn_s_barrier();

    for (int t = 0; t < LSTEPS; ++t) {
        float* xc = smem + XSOFF + ((t & 1) ? BB * XPL : 0);
        float* xn = smem + XSOFF + ((t & 1) ? 0 : BB * XPL);
        const float* As = A + (size_t)((t + 1 < LSTEPS) ? t + 1 : t) * (NDIM * NDIM);

        // phase-0 x reads (both batches): k-chunks m=s (k=4s) and m=16+s
        const f32x4 xva0 = *(const f32x4*)&xc[s * 4];
        const f32x4 xvb0 = *(const f32x4*)&xc[64 + s * 4];
        const f32x4 xva1 = *(const f32x4*)&xc[XPL + s * 4];
        const f32x4 xvb1 = *(const f32x4*)&xc[XPL + 64 + s * 4];

        float acc[4][BB];
#pragma unroll
        for (int i = 0; i < 4; ++i) { acc[i][0] = 0.f; acc[i][1] = 0.f; }

        // phase 0: consume H0 (m = s and m = 16+s over 4 rows, tri-masked)
#pragma unroll
        for (int i = 0; i < 4; ++i) {
            if (s <= mmax[i]) {
                const f32x4 a = *(const f32x4*)&Ab[a0base[i] + s * 4];
                acc[i][0] = fmaf(a[0], xva0[0], acc[i][0]);
                acc[i][0] = fmaf(a[1], xva0[1], acc[i][0]);
                acc[i][0] = fmaf(a[2], xva0[2], acc[i][0]);
                acc[i][0] = fmaf(a[3], xva0[3], acc[i][0]);
                acc[i][1] = fmaf(a[0], xva1[0], acc[i][1]);
                acc[i][1] = fmaf(a[1], xva1[1], acc[i][1]);
                acc[i][1] = fmaf(a[2], xva1[2], acc[i][1]);
                acc[i][1] = fmaf(a[3], xva1[3], acc[i][1]);
            }
        }
#pragma unroll
        for (int i = 0; i < 4; ++i) {
            if (16 + s <= mmax[i]) {
                const f32x4 a = *(const f32x4*)&Ab[a0base[i] + (16 + s) * 4];
                acc[i][0] = fmaf(a[0], xvb0[0], acc[i][0]);
                acc[i][0] = fmaf(a[1], xvb0[1], acc[i][0]);
                acc[i][0] = fmaf(a[2], xvb0[2], acc[i][0]);
                acc[i][0] = fmaf(a[3], xvb0[3], acc[i][0]);
                acc[i][1] = fmaf(a[0], xvb1[0], acc[i][1]);
                acc[i][1] = fmaf(a[1], xvb1[1], acc[i][1]);
                acc[i][1] = fmaf(a[2], xvb1[2], acc[i][1]);
                acc[i][1] = fmaf(a[3], xvb1[3], acc[i][1]);
            }
        }

        // H1^t DMA landed (vmcnt(0) exact here); barrier: all H0^t reads done.
        asm volatile("s_waitcnt vmcnt(0)" ::: "memory");
        asm volatile("s_waitcnt lgkmcnt(0)" ::: "memory");
        __builtin_amdgcn_s_barrier();

        // H0 region free -> issue H0^{t+1}
#pragma unroll
        for (int p = 0; p < H0ISS; ++p) gload_lds16(As + gsrc0[p], Ab + lbase0[p]);

        // scalars + coalesced out[t-1] stores (2 full 64B lines per wave)
        const float scal_in = inp[t * BATCH + b0 + bOwn];
        const float scal_b  = Bst[t * NDIM + rowOwn];
        if (t > 0 && lane < 32) {
            const int bi = lane >> 4, col = wave * 16 + (lane & 15);
            out[(size_t)(t - 1) * (BATCH * NDIM) + (size_t)(b0 + bi) * NDIM + col]
                = xc[bi * XPL + col];
        }

        // phase-1 x reads
        const f32x4 xvc0 = *(const f32x4*)&xc[128 + s * 4];
        const f32x4 xvd0 = *(const f32x4*)&xc[192 + s * 4];
        const f32x4 xvc1 = *(const f32x4*)&xc[XPL + 128 + s * 4];
        const f32x4 xvd1 = *(const f32x4*)&xc[XPL + 192 + s * 4];

        // phase 1: consume H1 (m = 32+s, 48+s; rows[2..3] only)
#pragma unroll
        for (int i = 2; i < 4; ++i) {
            if (32 + s <= mmax[i]) {
                const f32x4 a = *(const f32x4*)&Ab[a1base[i - 2] + (32 + s) * 4];
                acc[i][0] = fmaf(a[0], xvc0[0], acc[i][0]);
                acc[i][0] = fmaf(a[1], xvc0[1], acc[i][0]);
                acc[i][0] = fmaf(a[2], xvc0[2], acc[i][0]);
                acc[i][0] = fmaf(a[3], xvc0[3], acc[i][0]);
                acc[i][1] = fmaf(a[0], xvc1[0], acc[i][1]);
                acc[i][1] = fmaf(a[1], xvc1[1], acc[i][1]);
                acc[i][1] = fmaf(a[2], xvc1[2], acc[i][1]);
                acc[i][1] = fmaf(a[3], xvc1[3], acc[i][1]);
            }
            if (48 + s <= mmax[i]) {
                const f32x4 a = *(const f32x4*)&Ab[a1base[i - 2] + (48 + s) * 4];
                acc[i][0] = fmaf(a[0], xvd0[0], acc[i][0]);
                acc[i][0] = fmaf(a[1], xvd0[1], acc[i][0]);
                acc[i][0] = fmaf(a[2], xvd0[2], acc[i][0]);
                acc[i][0] = fmaf(a[3], xvd0[3], acc[i][0]);
                acc[i][1] = fmaf(a[0], xvd1[0], acc[i][1]);
                acc[i][1] = fmaf(a[1], xvd1[1], acc[i][1]);
                acc[i][1] = fmaf(a[2], xvd1[2], acc[i][1]);
                acc[i][1] = fmaf(a[3], xvd1[3], acc[i][1]);
            }
        }

        // all waves done with H1^t reads -> barrier -> issue H1^{t+1}
        asm volatile("s_waitcnt lgkmcnt(0)" ::: "memory");
        __builtin_amdgcn_s_barrier();
#pragma unroll
        for (int p = 0; p < H1ISS; ++p) gload_lds16(As + gsrc1[p], Ab + lbase1[p]);

        // BB=2 butterfly (R3-verbatim): sum 16 k-segs, redistribute to
        // (rowOwn, bOwn); lanes s>=8 hold duplicates, s<8 write.
        float c[4];
#pragma unroll
        for (int i = 0; i < 4; ++i) {
            const float keep = bOwn ? acc[i][1] : acc[i][0];
            const float send = bOwn ? acc[i][0] : acc[i][1];
            c[i] = keep + __shfl_xor(send, 1);
        }
        float d[2];
#pragma unroll
        for (int m = 0; m < 2; ++m) {
            const float keep = c[2 * m + sel1];
            const float send = c[2 * m + (1 - sel1)];
            d[m] = keep + __shfl_xor(send, 2);
        }
        const float e = d[sel2] + __shfl_xor(d[1 - sel2], 4);
        float v = e + __shfl_xor(e, 8);

        v = fmaf(scal_in, scal_b, v);
        if (writer) xn[bOwn * XPL + rowOwn] = v;

        // H0^{t+1} landed (newest 3 in flight = H1^{t+1}); x visible; barrier.
        asm volatile("s_waitcnt vmcnt(3)" ::: "memory");
        asm volatile("s_waitcnt lgkmcnt(0)" ::: "memory");
        __builtin_amdgcn_s_barrier();
    }

    // final row: x_{L-1} lives in plane 0 (L even)
    if (lane < 32) {
        const int bi = lane >> 4, col = wave * 16 + (lane & 15);
        out[(size_t)(LSTEPS - 1) * (BATCH * NDIM) + (size_t)(b0 + bi) * NDIM + col]
            = smem[XSOFF + bi * XPL + col];
    }
    asm volatile("s_waitcnt vmcnt(0)" ::: "memory");   // drain tail DMA
}

extern "C" void kernel_launch(void* const* d_in, const int* in_sizes, int n_in,
                              void* d_out, int out_size, void* d_ws, size_t ws_size,
                              hipStream_t stream) {
    const float* inp = (const float*)d_in[0];  // (L, BATCH) f32
    const float* A   = (const float*)d_in[1];  // (L, N, N)  f32
    const float* Bst = (const float*)d_in[2];  // (L, N)     f32
    float* out = (float*)d_out;                // (L, BATCH, N) f32
    (void)hipFuncSetAttribute((const void*)hippo_scan,
                              hipFuncAttributeMaxDynamicSharedMemorySize, SMEMB);
    hipLaunchKernelGGL(hippo_scan, dim3(NWG), dim3(THREADS), SMEMB, stream,
                       inp, A, Bst, out);
}